// Round 9
// baseline (334.874 us; speedup 1.0000x reference)
//
#include <hip/hip_runtime.h>
#include <hip/hip_bf16.h>

#define NFEAT 128
#define HID 256
#define BN_EPS 1e-5f
#define NBIN 64  // stats replica bins (atomic de-contention)

typedef __attribute__((ext_vector_type(8))) __bf16 bf16x8;
typedef __attribute__((ext_vector_type(4))) float f32x4;

static __device__ __forceinline__ float bflo(unsigned u) {
    union { unsigned x; float f; } c; c.x = u << 16; return c.f;
}
static __device__ __forceinline__ float bfhi(unsigned u) {
    union { unsigned x; float f; } c; c.x = u & 0xffff0000u; return c.f;
}

// ---------- CSR build ----------
__global__ void k_count(const int* __restrict__ ei, int E, int* __restrict__ cnt,
                        int* __restrict__ rank) {
    int e = blockIdx.x * blockDim.x + threadIdx.x;
    if (e < E) rank[e] = atomicAdd(&cnt[ei[E + e]], 1);
}

__global__ void k_scan1(const int* __restrict__ cnt, int n, int* __restrict__ partial,
                        int* __restrict__ blk_total) {
    __shared__ int sh[256];
    int i = blockIdx.x * 256 + threadIdx.x;
    int v = (i < n) ? cnt[i] : 0;
    sh[threadIdx.x] = v;
    __syncthreads();
    for (int off = 1; off < 256; off <<= 1) {
        int x = (threadIdx.x >= off) ? sh[threadIdx.x - off] : 0;
        __syncthreads();
        sh[threadIdx.x] += x;
        __syncthreads();
    }
    if (i < n) partial[i] = sh[threadIdx.x] - v;
    if (threadIdx.x == 255) blk_total[blockIdx.x] = sh[255];
}

// finalize with inline exclusive scan of blk_total (nblk <= 256)
__global__ void k_finalize(const int* __restrict__ partial, const int* __restrict__ blk_total,
                           const int* __restrict__ cnt, int n, int nblk,
                           int* __restrict__ row_start, float* __restrict__ dinv) {
    __shared__ int sw[4];
    const int t = threadIdx.x;
    const int b = blockIdx.x;
    int v = (t < b && t < nblk) ? blk_total[t] : 0;
#pragma unroll
    for (int m = 1; m < 64; m <<= 1) v += __shfl_xor(v, m);
    if ((t & 63) == 0) sw[t >> 6] = v;
    __syncthreads();
    int pref = sw[0] + sw[1] + sw[2] + sw[3];
    int i = b * 256 + t;
    if (i < n) {
        row_start[i] = partial[i] + pref;
        dinv[i] = rsqrtf((float)(cnt[i] + 1));
    }
}

// ---------- union: CSR-fill | x cast (full grid) | W1 transpose ----------
// All three depend only on k_finalize and are mutually independent -> one dispatch.
__global__ void k_fillcast(int fillBlocks, int castBlocks, const int* __restrict__ ei,
                           const int* __restrict__ rank, const int* __restrict__ row_start,
                           int E, int* __restrict__ col, const float* __restrict__ x,
                           const float* __restrict__ dinv, __hip_bfloat16* __restrict__ xs,
                           int n4, const float* __restrict__ W1,
                           __hip_bfloat16* __restrict__ Wt1) {
    const int bid = blockIdx.x;
    const int t = threadIdx.x;
    if (bid < fillBlocks) {  // CSR fill
        int e = bid * 256 + t;
        if (e < E) {
            int d = ei[E + e];
            col[row_start[d] + rank[e]] = ei[e];
        }
    } else if (bid < fillBlocks + castBlocks) {  // xs = dinv_row * x (bf16)
        int i = (bid - fillBlocks) * 256 + t;
        if (i < n4) {
            float d = dinv[i >> 5];  // 32 float4 groups per 128-ch row
            float4 v = *(const float4*)(x + (size_t)i * 4);
            __hip_bfloat16* o = xs + (size_t)i * 4;
            o[0] = __float2bfloat16(v.x * d);
            o[1] = __float2bfloat16(v.y * d);
            o[2] = __float2bfloat16(v.z * d);
            o[3] = __float2bfloat16(v.w * d);
        }
    } else {  // W1 transpose -> Wt1 [256][128]
        int idx = (bid - fillBlocks - castBlocks) * 256 + t;  // 0..32767
        int nn = idx & 255;
        int k = idx >> 8;
        Wt1[nn * 128 + k] = __float2bfloat16(W1[k * 256 + nn]);
    }
}

// ---------- merged BN1 fold + W-fold + uvec (one dispatch) ----------
__global__ __launch_bounds__(256) void k_bnfoldW(const float* __restrict__ gs,
                                                 const float* __restrict__ g,
                                                 const float* __restrict__ be,
                                                 const float* __restrict__ b, float invN,
                                                 const float* __restrict__ W1,
                                                 const float* __restrict__ W2,
                                                 __hip_bfloat16* __restrict__ WfT,
                                                 float* __restrict__ uvec) {
    __shared__ float shs[256], shb[256];
    const int c = threadIdx.x;
    float s = 0.f, q = 0.f;
    for (int r = 0; r < NBIN; r++) {
        s += gs[r * 512 + c];
        q += gs[r * 512 + 256 + c];
    }
    float mean = s * invN;
    float var = q * invN - mean * mean;
    float scl = rsqrtf(var + BN_EPS) * g[c];
    shs[c] = scl;
    shb[c] = (b[c] - mean) * scl + be[c];
    __syncthreads();
    if (blockIdx.x < 128) {
        int k = blockIdx.x;
        float acc = 0.f;
        for (int m = 0; m < 256; m++) acc += W1[k * 256 + m] * shs[m] * W2[m * 256 + c];
        WfT[(size_t)c * 128 + k] = __float2bfloat16(acc);
    } else {
        float acc = 0.f;
        for (int m = 0; m < 256; m++) acc += W2[m * 256 + c] * shb[m];
        uvec[c] = acc;
    }
}

// ---------- BN2 folded into final-GEMM B + bias (one dispatch) ----------
__global__ __launch_bounds__(256) void k_fold2(const float* __restrict__ gs,
                                               const float* __restrict__ g,
                                               const float* __restrict__ be, float invN,
                                               const float* __restrict__ Wfc,
                                               const float* __restrict__ bfc,
                                               __hip_bfloat16* __restrict__ Wtf,
                                               float* __restrict__ bias2) {
    __shared__ float shs[256], sho[256];
    const int c = threadIdx.x;
    float s = 0.f, q = 0.f;
    for (int r = 0; r < NBIN; r++) {
        s += gs[r * 512 + c];
        q += gs[r * 512 + 256 + c];
    }
    float mean = s * invN;
    float var = q * invN - mean * mean;
    float scl = rsqrtf(var + BN_EPS) * g[c];
    shs[c] = scl;
    sho[c] = (0.f - mean) * scl + be[c];
    __syncthreads();
    if (blockIdx.x < 256) {
        int k = blockIdx.x;
        Wtf[(size_t)c * 256 + k] = __float2bfloat16(Wfc[k * 256 + c] * shs[k]);
    } else {
        float acc = bfc[c];
        for (int m = 0; m < 256; m++) acc += sho[m] * Wfc[m * 256 + c];
        bias2[c] = acc;
    }
}

// ---------- wave-per-node SpMM body (C=128), round-6 proven 8-deep form ----------
// SCALE=false (pass 1): gathers pre-scaled rows, acc += v; rvec[i]=di*(di+sum dj).
// SCALE=true  (pass 2): gathers UNscaled rows, acc += dj*v (dj loads are off the
// critical path: issued alongside the row gathers, dinv is L2-resident).
template <bool SCALE>
static __device__ __forceinline__ void spmm_body(int wid, const __hip_bfloat16* __restrict__ Hs,
                                                 const int* __restrict__ rs,
                                                 const int* __restrict__ rc,
                                                 const int* __restrict__ col,
                                                 const float* __restrict__ dinv,
                                                 __hip_bfloat16* __restrict__ out,
                                                 float* __restrict__ rv, int N) {
    if (wid >= N) return;
    const int lane = threadIdx.x & 63;
    const int ch = lane * 2;
    const int s = rs[wid];
    const int deg = rc[wid];
    const float di = dinv[wid];

    unsigned u0 = *(const unsigned*)(Hs + (size_t)wid * 128 + ch);  // self-loop
    float a0, a1, dsum = 0.f;
    if constexpr (SCALE) { a0 = di * bflo(u0); a1 = di * bfhi(u0); }
    else { a0 = bflo(u0); a1 = bfhi(u0); }

    int e = 0;
    for (; e + 8 <= deg; e += 8) {
        int idx[8];
#pragma unroll
        for (int j = 0; j < 8; j++) idx[j] = col[s + e + j];
        float dj[8];
#pragma unroll
        for (int j = 0; j < 8; j++) dj[j] = dinv[idx[j]];
        unsigned u[8];
#pragma unroll
        for (int j = 0; j < 8; j++) u[j] = *(const unsigned*)(Hs + (size_t)idx[j] * 128 + ch);
#pragma unroll
        for (int j = 0; j < 8; j++) {
            if constexpr (SCALE) { a0 += dj[j] * bflo(u[j]); a1 += dj[j] * bfhi(u[j]); }
            else { a0 += bflo(u[j]); a1 += bfhi(u[j]); dsum += dj[j]; }
        }
    }
    for (; e < deg; e++) {
        int i0 = col[s + e];
        float d0 = dinv[i0];
        unsigned uu = *(const unsigned*)(Hs + (size_t)i0 * 128 + ch);
        if constexpr (SCALE) { a0 += d0 * bflo(uu); a1 += d0 * bfhi(uu); }
        else { a0 += bflo(uu); a1 += bfhi(uu); dsum += d0; }
    }
    union { unsigned w; unsigned short us[2]; } o;
    __hip_bfloat16 b0 = __float2bfloat16(di * a0); o.us[0] = *(unsigned short*)&b0;
    __hip_bfloat16 b1 = __float2bfloat16(di * a1); o.us[1] = *(unsigned short*)&b1;
    *(unsigned*)(out + (size_t)wid * 128 + ch) = o.w;
    if (!SCALE && rv && lane == 0) rv[wid] = di * (di + dsum);
}

template <bool SCALE>
__global__ __launch_bounds__(256) void k_spmm(const __hip_bfloat16* __restrict__ Hs,
                                              const int* __restrict__ rs,
                                              const int* __restrict__ rc,
                                              const int* __restrict__ col,
                                              const float* __restrict__ dinv,
                                              __hip_bfloat16* __restrict__ out,
                                              float* __restrict__ rv, int N) {
    spmm_body<SCALE>(blockIdx.x * 4 + (threadIdx.x >> 6), Hs, rs, rc, col, dinv, out, rv, N);
}

// ---------- chunked double-buffered MFMA GEMM body, 128-row tile ----------
// out[M][256] = A[M][K] @ B[K][256] + bias (+ rank-1 rvec*uvec^T);
// optional bf16/fp32 out; optional fused BN stats (atomics into NBIN replica bins).
// Tile = 128 rows x 128 cols at (bx, by). K staged in 64-wide chunks, double-buffered
// LDS (36.9 KB); A fragments ping-pong chunk-wise. Stats alias dead B buffer.
template <int K, bool STATS>
static __device__ __forceinline__ void gemm_body(unsigned short* Bs, int bx, int by,
                                                 const __hip_bfloat16* __restrict__ A,
                                                 const __hip_bfloat16* __restrict__ Bt,
                                                 const float* __restrict__ bias,
                                                 __hip_bfloat16* __restrict__ outb,
                                                 float* __restrict__ outf,
                                                 float* __restrict__ gs,
                                                 const float* __restrict__ rvec,
                                                 const float* __restrict__ uvec, int M) {
    constexpr int NC = K / 64;   // 64-wide K chunks
    constexpr int LDR = 72;      // chunk row stride (elems)
    float* sred = (float*)Bs;    // aliases Bs after all MFMA reads + barrier
    float* qred = sred + 512;

    const int t = threadIdx.x;
    const int wv = t >> 6;
    const int lane = t & 63;
    const int mlane = lane & 15;
    const int quad = lane >> 4;
    const int m0 = bx * 128;
    const int n0 = by * 128;
    const int arow0 = m0 + wv * 32 + mlane;  // mt adds +16

    auto stage = [&](int c, int buf) {
#pragma unroll
        for (int i = 0; i < 4; i++) {
            int idx = t + i * 256;
            int row = idx >> 3;
            int c4 = idx & 7;
            uint4 v = *(const uint4*)(Bt + (size_t)(n0 + row) * K + c * 64 + c4 * 8);
            *(uint4*)(Bs + buf * (128 * LDR) + row * LDR + c4 * 8) = v;
        }
    };
    auto loadA = [&](int c, bf16x8 (&dst)[2][2]) {
#pragma unroll
        for (int mt = 0; mt < 2; mt++)
#pragma unroll
            for (int ks = 0; ks < 2; ks++)
                dst[mt][ks] = *(const bf16x8*)(A + (size_t)(arow0 + mt * 16) * K + c * 64 +
                                               ks * 32 + quad * 8);
    };

    f32x4 acc[2][8];
#pragma unroll
    for (int mt = 0; mt < 2; mt++)
#pragma unroll
        for (int i = 0; i < 8; i++) acc[mt][i] = (f32x4){0.f, 0.f, 0.f, 0.f};

    bf16x8 aP[2][2], aQ[2][2];
    loadA(0, aP);
    stage(0, 0);

    auto mmachunk = [&](int c, bf16x8 (&ac)[2][2]) {
        const unsigned short* base = Bs + (c & 1) * (128 * LDR);
#pragma unroll
        for (int nt = 0; nt < 8; nt++) {
            const unsigned short* bp = base + (nt * 16 + mlane) * LDR + quad * 8;
#pragma unroll
            for (int ks = 0; ks < 2; ks++) {
                bf16x8 b = *(const bf16x8*)(bp + ks * 32);  // one LDS read, two MFMAs
                acc[0][nt] = __builtin_amdgcn_mfma_f32_16x16x32_bf16(ac[0][ks], b, acc[0][nt], 0, 0, 0);
                acc[1][nt] = __builtin_amdgcn_mfma_f32_16x16x32_bf16(ac[1][ks], b, acc[1][nt], 0, 0, 0);
            }
        }
    };

#pragma unroll
    for (int c = 0; c < NC; c++) {
        __syncthreads();
        if (c + 1 < NC) {
            stage(c + 1, (c + 1) & 1);
            if ((c & 1) == 0) loadA(c + 1, aQ); else loadA(c + 1, aP);
        }
        if ((c & 1) == 0) mmachunk(c, aP); else mmachunk(c, aQ);
    }

    // C/D mapping: col = lane&15, row = quad*4 + reg
    float rv[2][4] = {{0.f, 0.f, 0.f, 0.f}, {0.f, 0.f, 0.f, 0.f}};
    if (rvec) {
#pragma unroll
        for (int mt = 0; mt < 2; mt++)
#pragma unroll
            for (int r = 0; r < 4; r++) {
                int row = m0 + wv * 32 + mt * 16 + quad * 4 + r;
                if (row < M) rv[mt][r] = rvec[row];
            }
    }
    float sp[8], qp[8];
#pragma unroll
    for (int nt = 0; nt < 8; nt++) {
        int colx = n0 + nt * 16 + mlane;
        float bv = bias[colx];
        float uvn = uvec ? uvec[colx] : 0.f;
        float s = 0.f, q = 0.f;
#pragma unroll
        for (int mt = 0; mt < 2; mt++)
#pragma unroll
            for (int r = 0; r < 4; r++) {
                int row = m0 + wv * 32 + mt * 16 + quad * 4 + r;
                if (row < M) {
                    float h = acc[mt][nt][r] + bv + rv[mt][r] * uvn;
                    if (outb) outb[(size_t)row * HID + colx] = __float2bfloat16(h);
                    if (outf) outf[(size_t)row * HID + colx] = h;
                    s += h;
                    q += h * h;
                }
            }
        sp[nt] = s;
        qp[nt] = q;
    }
    if constexpr (STATS) {
#pragma unroll
        for (int nt = 0; nt < 8; nt++) {
            sp[nt] += __shfl_xor(sp[nt], 16);
            sp[nt] += __shfl_xor(sp[nt], 32);
            qp[nt] += __shfl_xor(qp[nt], 16);
            qp[nt] += __shfl_xor(qp[nt], 32);
        }
        __syncthreads();  // all MFMA reads of Bs done -> safe to alias
        if (quad == 0) {
#pragma unroll
            for (int nt = 0; nt < 8; nt++) {
                sred[wv * 128 + nt * 16 + mlane] = sp[nt];
                qred[wv * 128 + nt * 16 + mlane] = qp[nt];
            }
        }
        __syncthreads();
        if (t < 128) {
            float ss = sred[t] + sred[128 + t] + sred[256 + t] + sred[384 + t];
            float qq = qred[t] + qred[128 + t] + qred[256 + t] + qred[384 + t];
            float* bin = gs + (bx & (NBIN - 1)) * 512;  // de-contended replicas
            atomicAdd(&bin[n0 + t], ss);
            atomicAdd(&bin[256 + n0 + t], qq);
        }
    }
}

template <int K, bool STATS>
__global__ __launch_bounds__(256, 4) void k_gemm2(const __hip_bfloat16* __restrict__ A,
                                                  const __hip_bfloat16* __restrict__ Bt,
                                                  const float* __restrict__ bias,
                                                  __hip_bfloat16* __restrict__ outb,
                                                  float* __restrict__ outf,
                                                  float* __restrict__ gs,
                                                  const float* __restrict__ rvec,
                                                  const float* __restrict__ uvec, int M) {
    __shared__ __align__(16) unsigned short Bs[2 * 128 * 72];
    gemm_body<K, STATS>(Bs, blockIdx.x, blockIdx.y, A, Bt, bias, outb, outf, gs, rvec, uvec, M);
}

// ---------- union: gemm1 (BN1 stats) ∥ spmm2 — both depend only on aggX ----------
// gemm blocks FIRST (gb = tiles*2), spmm blocks behind: the ~12 µs stats-GEMM runs
// in the shadow of spmm2's ~43 µs gather phase instead of serializing after it.
__global__ __launch_bounds__(256, 4) void k_mid(int gb, const __hip_bfloat16* __restrict__ aggX,
                                                const __hip_bfloat16* __restrict__ Wt1,
                                                const float* __restrict__ b1,
                                                float* __restrict__ gs1,
                                                const int* __restrict__ rs,
                                                const int* __restrict__ rc,
                                                const int* __restrict__ col,
                                                const float* __restrict__ dinv,
                                                __hip_bfloat16* __restrict__ t2, int N) {
    __shared__ __align__(16) unsigned short Bs[2 * 128 * 72];
    if ((int)blockIdx.x < gb) {
        gemm_body<NFEAT, true>(Bs, blockIdx.x >> 1, blockIdx.x & 1, aggX, Wt1, b1,
                               nullptr, nullptr, gs1, nullptr, nullptr, N);
    } else {
        spmm_body<true>((blockIdx.x - gb) * 4 + (threadIdx.x >> 6), aggX, rs, rc, col, dinv,
                        t2, nullptr, N);
    }
}

extern "C" void kernel_launch(void* const* d_in, const int* in_sizes, int n_in, void* d_out,
                              int out_size, void* d_ws, size_t ws_size, hipStream_t stream) {
    const float* x = (const float*)d_in[0];
    const int* ei = (const int*)d_in[1];
    const float* W1 = (const float*)d_in[2];
    const float* b1 = (const float*)d_in[3];
    const float* g1 = (const float*)d_in[4];
    const float* be1 = (const float*)d_in[5];
    const float* W2 = (const float*)d_in[6];
    const float* b2 = (const float*)d_in[7];
    const float* g2 = (const float*)d_in[8];
    const float* be2 = (const float*)d_in[9];
    const float* Wfc = (const float*)d_in[10];
    const float* bfc = (const float*)d_in[11];
    float* out = (float*)d_out;

    const int N = in_sizes[0] / NFEAT;  // 50000
    const int E = in_sizes[1] / 2;      // 800000
    const float invN = 1.0f / (float)N;

    char* ws = (char*)d_ws;
    size_t off = 0;
    auto alloc = [&](size_t bytes) -> void* {
        void* p = ws + off;
        off += (bytes + 255) & ~(size_t)255;
        return p;
    };
    // row_cnt + gs1 + gs2 contiguous -> single memset
    int* row_cnt = (int*)alloc((size_t)N * 4);
    float* gs1 = (float*)alloc((size_t)NBIN * 512 * 4);
    float* gs2 = (float*)alloc((size_t)NBIN * 512 * 4);
    size_t zero_bytes = off;
    int* partial = (int*)alloc((size_t)N * 4);
    int* row_start = (int*)alloc((size_t)N * 4);
    int* blk = (int*)alloc(256 * 4);
    float* dinv = (float*)alloc((size_t)N * 4);
    int* rank = (int*)alloc((size_t)E * 4);
    int* col_idx = (int*)alloc((size_t)E * 4);
    float* uvec = (float*)alloc(256 * 4);
    float* bias2 = (float*)alloc(256 * 4);
    float* rvec = (float*)alloc((size_t)(N + 128) * 4);
    __hip_bfloat16* Wt1 = (__hip_bfloat16*)alloc(256 * 128 * 2);
    __hip_bfloat16* Wtf = (__hip_bfloat16*)alloc(256 * 256 * 2);
    __hip_bfloat16* WfT = (__hip_bfloat16*)alloc(256 * 128 * 2);
    // node buffers padded by 128 rows (GEMM A-fragment overread of last 128-row block)
    __hip_bfloat16* xs = (__hip_bfloat16*)alloc((size_t)(N + 128) * NFEAT * 2);
    __hip_bfloat16* aggX = (__hip_bfloat16*)alloc((size_t)(N + 128) * NFEAT * 2);
    __hip_bfloat16* h2 = (__hip_bfloat16*)alloc((size_t)(N + 128) * HID * 2);
    __hip_bfloat16* t2 = xs;  // xs dead after spmm1

    hipMemsetAsync(row_cnt, 0, zero_bytes, stream);  // row_cnt + gs1 + gs2 in one fill

    const int nblk = (N + 255) / 256;
    const int fillBlocks = (E + 255) / 256;
    const int castBlocks = (N * NFEAT / 4 + 255) / 256;

    // CSR build: count -> scan -> finalize -> {fill ∥ cast ∥ W1-transpose}
    k_count<<<fillBlocks, 256, 0, stream>>>(ei, E, row_cnt, rank);
    k_scan1<<<nblk, 256, 0, stream>>>(row_cnt, N, partial, blk);
    k_finalize<<<nblk, 256, 0, stream>>>(partial, blk, row_cnt, N, nblk, row_start, dinv);
    k_fillcast<<<fillBlocks + castBlocks + 128, 256, 0, stream>>>(
        fillBlocks, castBlocks, ei, rank, row_start, E, col_idx, x, dinv, xs,
        N * NFEAT / 4, W1, Wt1);

    const int sg = (N + 3) / 4;
    dim3 gg((N + 127) / 128, 2);
    const int gb = ((N + 127) / 128) * 2;  // gemm tile count (1D-mapped)

    // t1 = A_hat * x -> aggX (+ fused rvec)
    k_spmm<false><<<sg, 256, 0, stream>>>(xs, row_start, row_cnt, col_idx, dinv, aggX, rvec, N);
    // gemm1 stats (aggX@W1+b1 -> gs1 bins) ∥ t2 = A_hat * t1 (gathers aggX, dj on the fly)
    k_mid<<<gb + sg, 256, 0, stream>>>(gb, aggX, Wt1, b1, gs1, row_start, row_cnt, col_idx,
                                       dinv, t2, N);
    // BN1 fold + WfT = W1*diag(sc1)*W2 + uvec
    k_bnfoldW<<<129, 256, 0, stream>>>(gs1, g1, be1, b1, invN, W1, W2, WfT, uvec);
    // h2pre = t2 @ WfT + rvec*uvec^T + b2, fused BN2 stats
    k_gemm2<NFEAT, true><<<gg, 256, 0, stream>>>(t2, WfT, b2, h2, nullptr, gs2, rvec, uvec, N);
    // BN2 folded into B side: Wtf = diag(sc2)*Wfc (Bt layout), bias2 = of2^T Wfc + bfc
    k_fold2<<<257, 256, 0, stream>>>(gs2, g2, be2, invN, Wfc, bfc, Wtf, bias2);
    // out = h2 @ Wtf + bias2 (plain GEMM, fp32 out)
    k_gemm2<HID, false><<<gg, 256, 0, stream>>>(h2, Wtf, bias2, nullptr, out, nullptr,
                                                nullptr, nullptr, N);
}

// Round 10
// 313.908 us; speedup vs baseline: 1.0668x; 1.0668x over previous
//
#include <hip/hip_runtime.h>
#include <hip/hip_bf16.h>

#define NFEAT 128
#define HID 256
#define BN_EPS 1e-5f
#define NBIN 64  // stats replica bins (atomic de-contention)

typedef __attribute__((ext_vector_type(8))) __bf16 bf16x8;
typedef __attribute__((ext_vector_type(4))) float f32x4;

static __device__ __forceinline__ float bflo(unsigned u) {
    union { unsigned x; float f; } c; c.x = u << 16; return c.f;
}
static __device__ __forceinline__ float bfhi(unsigned u) {
    union { unsigned x; float f; } c; c.x = u & 0xffff0000u; return c.f;
}

// ---------- CSR build ----------
__global__ void k_count(const int* __restrict__ ei, int E, int* __restrict__ cnt,
                        int* __restrict__ rank) {
    int e = blockIdx.x * blockDim.x + threadIdx.x;
    if (e < E) rank[e] = atomicAdd(&cnt[ei[E + e]], 1);
}

__global__ void k_scan1(const int* __restrict__ cnt, int n, int* __restrict__ partial,
                        int* __restrict__ blk_total) {
    __shared__ int sh[256];
    int i = blockIdx.x * 256 + threadIdx.x;
    int v = (i < n) ? cnt[i] : 0;
    sh[threadIdx.x] = v;
    __syncthreads();
    for (int off = 1; off < 256; off <<= 1) {
        int x = (threadIdx.x >= off) ? sh[threadIdx.x - off] : 0;
        __syncthreads();
        sh[threadIdx.x] += x;
        __syncthreads();
    }
    if (i < n) partial[i] = sh[threadIdx.x] - v;
    if (threadIdx.x == 255) blk_total[blockIdx.x] = sh[255];
}

// finalize with inline exclusive scan of blk_total (nblk <= 256)
__global__ void k_finalize(const int* __restrict__ partial, const int* __restrict__ blk_total,
                           const int* __restrict__ cnt, int n, int nblk,
                           int* __restrict__ row_start, float* __restrict__ dinv) {
    __shared__ int sw[4];
    const int t = threadIdx.x;
    const int b = blockIdx.x;
    int v = (t < b && t < nblk) ? blk_total[t] : 0;
#pragma unroll
    for (int m = 1; m < 64; m <<= 1) v += __shfl_xor(v, m);
    if ((t & 63) == 0) sw[t >> 6] = v;
    __syncthreads();
    int pref = sw[0] + sw[1] + sw[2] + sw[3];
    int i = b * 256 + t;
    if (i < n) {
        row_start[i] = partial[i] + pref;
        dinv[i] = rsqrtf((float)(cnt[i] + 1));
    }
}

// ---------- union: CSR-fill | x cast (full grid) | W1 transpose ----------
// All three depend only on k_finalize, are mutually independent, and have IDENTICAL
// lean resource footprints (0 LDS, low VGPR) -> safe block-role union, one dispatch.
__global__ void k_fillcast(int fillBlocks, int castBlocks, const int* __restrict__ ei,
                           const int* __restrict__ rank, const int* __restrict__ row_start,
                           int E, int* __restrict__ col, const float* __restrict__ x,
                           const float* __restrict__ dinv, __hip_bfloat16* __restrict__ xs,
                           int n4, const float* __restrict__ W1,
                           __hip_bfloat16* __restrict__ Wt1) {
    const int bid = blockIdx.x;
    const int t = threadIdx.x;
    if (bid < fillBlocks) {  // CSR fill
        int e = bid * 256 + t;
        if (e < E) {
            int d = ei[E + e];
            col[row_start[d] + rank[e]] = ei[e];
        }
    } else if (bid < fillBlocks + castBlocks) {  // xs = dinv_row * x (bf16)
        int i = (bid - fillBlocks) * 256 + t;
        if (i < n4) {
            float d = dinv[i >> 5];  // 32 float4 groups per 128-ch row
            float4 v = *(const float4*)(x + (size_t)i * 4);
            __hip_bfloat16* o = xs + (size_t)i * 4;
            o[0] = __float2bfloat16(v.x * d);
            o[1] = __float2bfloat16(v.y * d);
            o[2] = __float2bfloat16(v.z * d);
            o[3] = __float2bfloat16(v.w * d);
        }
    } else {  // W1 transpose -> Wt1 [256][128]
        int idx = (bid - fillBlocks - castBlocks) * 256 + t;  // 0..32767
        int nn = idx & 255;
        int k = idx >> 8;
        Wt1[nn * 128 + k] = __float2bfloat16(W1[k * 256 + nn]);
    }
}

// ---------- merged BN1 fold + W-fold + uvec (one dispatch) ----------
__global__ __launch_bounds__(256) void k_bnfoldW(const float* __restrict__ gs,
                                                 const float* __restrict__ g,
                                                 const float* __restrict__ be,
                                                 const float* __restrict__ b, float invN,
                                                 const float* __restrict__ W1,
                                                 const float* __restrict__ W2,
                                                 __hip_bfloat16* __restrict__ WfT,
                                                 float* __restrict__ uvec) {
    __shared__ float shs[256], shb[256];
    const int c = threadIdx.x;
    float s = 0.f, q = 0.f;
    for (int r = 0; r < NBIN; r++) {
        s += gs[r * 512 + c];
        q += gs[r * 512 + 256 + c];
    }
    float mean = s * invN;
    float var = q * invN - mean * mean;
    float scl = rsqrtf(var + BN_EPS) * g[c];
    shs[c] = scl;
    shb[c] = (b[c] - mean) * scl + be[c];
    __syncthreads();
    if (blockIdx.x < 128) {
        int k = blockIdx.x;
        float acc = 0.f;
        for (int m = 0; m < 256; m++) acc += W1[k * 256 + m] * shs[m] * W2[m * 256 + c];
        WfT[(size_t)c * 128 + k] = __float2bfloat16(acc);
    } else {
        float acc = 0.f;
        for (int m = 0; m < 256; m++) acc += W2[m * 256 + c] * shb[m];
        uvec[c] = acc;
    }
}

// ---------- BN2 folded into final-GEMM B + bias (one dispatch) ----------
__global__ __launch_bounds__(256) void k_fold2(const float* __restrict__ gs,
                                               const float* __restrict__ g,
                                               const float* __restrict__ be, float invN,
                                               const float* __restrict__ Wfc,
                                               const float* __restrict__ bfc,
                                               __hip_bfloat16* __restrict__ Wtf,
                                               float* __restrict__ bias2) {
    __shared__ float shs[256], sho[256];
    const int c = threadIdx.x;
    float s = 0.f, q = 0.f;
    for (int r = 0; r < NBIN; r++) {
        s += gs[r * 512 + c];
        q += gs[r * 512 + 256 + c];
    }
    float mean = s * invN;
    float var = q * invN - mean * mean;
    float scl = rsqrtf(var + BN_EPS) * g[c];
    shs[c] = scl;
    sho[c] = (0.f - mean) * scl + be[c];
    __syncthreads();
    if (blockIdx.x < 256) {
        int k = blockIdx.x;
        Wtf[(size_t)c * 256 + k] = __float2bfloat16(Wfc[k * 256 + c] * shs[k]);
    } else {
        float acc = bfc[c];
        for (int m = 0; m < 256; m++) acc += sho[m] * Wfc[m * 256 + c];
        bias2[c] = acc;
    }
}

// ---------- wave-per-node SpMM (C=128), round-6 proven 8-deep form ----------
// SCALE=false (pass 1): gathers pre-scaled rows, acc += v; rvec[i]=di*(di+sum dj).
// SCALE=true  (pass 2): gathers UNscaled rows, acc += dj*v (dj loads off the critical
// path: issued alongside the row gathers, dinv is L2-resident).
template <bool SCALE>
__global__ __launch_bounds__(256) void k_spmm(const __hip_bfloat16* __restrict__ Hs,
                                              const int* __restrict__ rs,
                                              const int* __restrict__ rc,
                                              const int* __restrict__ col,
                                              const float* __restrict__ dinv,
                                              __hip_bfloat16* __restrict__ out,
                                              float* __restrict__ rv, int N) {
    const int wid = blockIdx.x * 4 + (threadIdx.x >> 6);
    if (wid >= N) return;
    const int lane = threadIdx.x & 63;
    const int ch = lane * 2;
    const int s = rs[wid];
    const int deg = rc[wid];
    const float di = dinv[wid];

    unsigned u0 = *(const unsigned*)(Hs + (size_t)wid * 128 + ch);  // self-loop
    float a0, a1, dsum = 0.f;
    if constexpr (SCALE) { a0 = di * bflo(u0); a1 = di * bfhi(u0); }
    else { a0 = bflo(u0); a1 = bfhi(u0); }

    int e = 0;
    for (; e + 8 <= deg; e += 8) {
        int idx[8];
#pragma unroll
        for (int j = 0; j < 8; j++) idx[j] = col[s + e + j];
        float dj[8];
#pragma unroll
        for (int j = 0; j < 8; j++) dj[j] = dinv[idx[j]];
        unsigned u[8];
#pragma unroll
        for (int j = 0; j < 8; j++) u[j] = *(const unsigned*)(Hs + (size_t)idx[j] * 128 + ch);
#pragma unroll
        for (int j = 0; j < 8; j++) {
            if constexpr (SCALE) { a0 += dj[j] * bflo(u[j]); a1 += dj[j] * bfhi(u[j]); }
            else { a0 += bflo(u[j]); a1 += bfhi(u[j]); dsum += dj[j]; }
        }
    }
    for (; e < deg; e++) {
        int i0 = col[s + e];
        float d0 = dinv[i0];
        unsigned uu = *(const unsigned*)(Hs + (size_t)i0 * 128 + ch);
        if constexpr (SCALE) { a0 += d0 * bflo(uu); a1 += d0 * bfhi(uu); }
        else { a0 += bflo(uu); a1 += bfhi(uu); dsum += d0; }
    }
    union { unsigned w; unsigned short us[2]; } o;
    __hip_bfloat16 b0 = __float2bfloat16(di * a0); o.us[0] = *(unsigned short*)&b0;
    __hip_bfloat16 b1 = __float2bfloat16(di * a1); o.us[1] = *(unsigned short*)&b1;
    *(unsigned*)(out + (size_t)wid * 128 + ch) = o.w;
    if (!SCALE && rv && lane == 0) rv[wid] = di * (di + dsum);
}

// ---------- chunked double-buffered MFMA GEMM, 128-row tile, 4 blocks/CU ----------
// out[M][256] = A[M][K] @ B[K][256] + bias (+ rank-1 rvec*uvec^T);
// optional bf16/fp32 out; optional fused BN stats (atomics into NBIN replica bins).
// Block = 128 rows x 128 cols, grid (ceil(M/128), 2). K staged in 64-wide chunks,
// double-buffered LDS (36.9 KB); A fragments ping-pong chunk-wise. Stats alias dead
// B buffer. Last block reads A rows >= M (buffers padded by 128; guard discards).
template <int K, bool STATS>
__global__ __launch_bounds__(256, 4) void k_gemm2(const __hip_bfloat16* __restrict__ A,
                                                  const __hip_bfloat16* __restrict__ Bt,
                                                  const float* __restrict__ bias,
                                                  __hip_bfloat16* __restrict__ outb,
                                                  float* __restrict__ outf,
                                                  float* __restrict__ gs,
                                                  const float* __restrict__ rvec,
                                                  const float* __restrict__ uvec, int M) {
    constexpr int NC = K / 64;   // 64-wide K chunks
    constexpr int LDR = 72;      // chunk row stride (elems)
    __shared__ __align__(16) unsigned short Bs[2 * 128 * LDR];
    float* sred = (float*)Bs;    // aliases Bs after all MFMA reads + barrier
    float* qred = sred + 512;

    const int t = threadIdx.x;
    const int wv = t >> 6;
    const int lane = t & 63;
    const int mlane = lane & 15;
    const int quad = lane >> 4;
    const int m0 = blockIdx.x * 128;
    const int n0 = blockIdx.y * 128;
    const int arow0 = m0 + wv * 32 + mlane;  // mt adds +16

    auto stage = [&](int c, int buf) {
#pragma unroll
        for (int i = 0; i < 4; i++) {
            int idx = t + i * 256;
            int row = idx >> 3;
            int c4 = idx & 7;
            uint4 v = *(const uint4*)(Bt + (size_t)(n0 + row) * K + c * 64 + c4 * 8);
            *(uint4*)(Bs + buf * (128 * LDR) + row * LDR + c4 * 8) = v;
        }
    };
    auto loadA = [&](int c, bf16x8 (&dst)[2][2]) {
#pragma unroll
        for (int mt = 0; mt < 2; mt++)
#pragma unroll
            for (int ks = 0; ks < 2; ks++)
                dst[mt][ks] = *(const bf16x8*)(A + (size_t)(arow0 + mt * 16) * K + c * 64 +
                                               ks * 32 + quad * 8);
    };

    f32x4 acc[2][8];
#pragma unroll
    for (int mt = 0; mt < 2; mt++)
#pragma unroll
        for (int i = 0; i < 8; i++) acc[mt][i] = (f32x4){0.f, 0.f, 0.f, 0.f};

    bf16x8 aP[2][2], aQ[2][2];  // ping-pong A chunk fragments
    loadA(0, aP);
    stage(0, 0);

    auto mmachunk = [&](int c, bf16x8 (&ac)[2][2]) {
        const unsigned short* base = Bs + (c & 1) * (128 * LDR);
#pragma unroll
        for (int nt = 0; nt < 8; nt++) {
            const unsigned short* bp = base + (nt * 16 + mlane) * LDR + quad * 8;
#pragma unroll
            for (int ks = 0; ks < 2; ks++) {
                bf16x8 b = *(const bf16x8*)(bp + ks * 32);  // one LDS read, two MFMAs
                acc[0][nt] = __builtin_amdgcn_mfma_f32_16x16x32_bf16(ac[0][ks], b, acc[0][nt], 0, 0, 0);
                acc[1][nt] = __builtin_amdgcn_mfma_f32_16x16x32_bf16(ac[1][ks], b, acc[1][nt], 0, 0, 0);
            }
        }
    };

#pragma unroll
    for (int c = 0; c < NC; c++) {
        __syncthreads();  // buf[c&1] staged; previous reads of buf[(c+1)&1] done
        if (c + 1 < NC) {
            stage(c + 1, (c + 1) & 1);
            if ((c & 1) == 0) loadA(c + 1, aQ); else loadA(c + 1, aP);
        }
        if ((c & 1) == 0) mmachunk(c, aP); else mmachunk(c, aQ);
    }

    // C/D mapping: col = lane&15, row = quad*4 + reg
    float rv[2][4] = {{0.f, 0.f, 0.f, 0.f}, {0.f, 0.f, 0.f, 0.f}};
    if (rvec) {
#pragma unroll
        for (int mt = 0; mt < 2; mt++)
#pragma unroll
            for (int r = 0; r < 4; r++) {
                int row = m0 + wv * 32 + mt * 16 + quad * 4 + r;
                if (row < M) rv[mt][r] = rvec[row];
            }
    }
    float sp[8], qp[8];
#pragma unroll
    for (int nt = 0; nt < 8; nt++) {
        int colx = n0 + nt * 16 + mlane;
        float bv = bias[colx];
        float uvn = uvec ? uvec[colx] : 0.f;
        float s = 0.f, q = 0.f;
#pragma unroll
        for (int mt = 0; mt < 2; mt++)
#pragma unroll
            for (int r = 0; r < 4; r++) {
                int row = m0 + wv * 32 + mt * 16 + quad * 4 + r;
                if (row < M) {
                    float h = acc[mt][nt][r] + bv + rv[mt][r] * uvn;
                    if (outb) outb[(size_t)row * HID + colx] = __float2bfloat16(h);
                    if (outf) outf[(size_t)row * HID + colx] = h;
                    s += h;
                    q += h * h;
                }
            }
        sp[nt] = s;
        qp[nt] = q;
    }
    if constexpr (STATS) {
#pragma unroll
        for (int nt = 0; nt < 8; nt++) {
            sp[nt] += __shfl_xor(sp[nt], 16);
            sp[nt] += __shfl_xor(sp[nt], 32);
            qp[nt] += __shfl_xor(qp[nt], 16);
            qp[nt] += __shfl_xor(qp[nt], 32);
        }
        __syncthreads();  // all MFMA reads of Bs done -> safe to alias
        if (quad == 0) {
#pragma unroll
            for (int nt = 0; nt < 8; nt++) {
                sred[wv * 128 + nt * 16 + mlane] = sp[nt];
                qred[wv * 128 + nt * 16 + mlane] = qp[nt];
            }
        }
        __syncthreads();
        if (t < 128) {
            float ss = sred[t] + sred[128 + t] + sred[256 + t] + sred[384 + t];
            float qq = qred[t] + qred[128 + t] + qred[256 + t] + qred[384 + t];
            float* bin = gs + (blockIdx.x & (NBIN - 1)) * 512;  // de-contended replicas
            atomicAdd(&bin[n0 + t], ss);
            atomicAdd(&bin[256 + n0 + t], qq);
        }
    }
}

extern "C" void kernel_launch(void* const* d_in, const int* in_sizes, int n_in, void* d_out,
                              int out_size, void* d_ws, size_t ws_size, hipStream_t stream) {
    const float* x = (const float*)d_in[0];
    const int* ei = (const int*)d_in[1];
    const float* W1 = (const float*)d_in[2];
    const float* b1 = (const float*)d_in[3];
    const float* g1 = (const float*)d_in[4];
    const float* be1 = (const float*)d_in[5];
    const float* W2 = (const float*)d_in[6];
    const float* b2 = (const float*)d_in[7];
    const float* g2 = (const float*)d_in[8];
    const float* be2 = (const float*)d_in[9];
    const float* Wfc = (const float*)d_in[10];
    const float* bfc = (const float*)d_in[11];
    float* out = (float*)d_out;

    const int N = in_sizes[0] / NFEAT;  // 50000
    const int E = in_sizes[1] / 2;      // 800000
    const float invN = 1.0f / (float)N;

    char* ws = (char*)d_ws;
    size_t off = 0;
    auto alloc = [&](size_t bytes) -> void* {
        void* p = ws + off;
        off += (bytes + 255) & ~(size_t)255;
        return p;
    };
    // row_cnt + gs1 + gs2 contiguous -> single memset
    int* row_cnt = (int*)alloc((size_t)N * 4);
    float* gs1 = (float*)alloc((size_t)NBIN * 512 * 4);
    float* gs2 = (float*)alloc((size_t)NBIN * 512 * 4);
    size_t zero_bytes = off;
    int* partial = (int*)alloc((size_t)N * 4);
    int* row_start = (int*)alloc((size_t)N * 4);
    int* blk = (int*)alloc(256 * 4);
    float* dinv = (float*)alloc((size_t)N * 4);
    int* rank = (int*)alloc((size_t)E * 4);
    int* col_idx = (int*)alloc((size_t)E * 4);
    float* uvec = (float*)alloc(256 * 4);
    float* bias2 = (float*)alloc(256 * 4);
    float* rvec = (float*)alloc((size_t)(N + 128) * 4);
    __hip_bfloat16* Wt1 = (__hip_bfloat16*)alloc(256 * 128 * 2);
    __hip_bfloat16* Wtf = (__hip_bfloat16*)alloc(256 * 256 * 2);
    __hip_bfloat16* WfT = (__hip_bfloat16*)alloc(256 * 128 * 2);
    // node buffers padded by 128 rows (GEMM A-fragment overread of last 128-row block)
    __hip_bfloat16* xs = (__hip_bfloat16*)alloc((size_t)(N + 128) * NFEAT * 2);
    __hip_bfloat16* aggX = (__hip_bfloat16*)alloc((size_t)(N + 128) * NFEAT * 2);
    __hip_bfloat16* h2 = (__hip_bfloat16*)alloc((size_t)(N + 128) * HID * 2);
    __hip_bfloat16* t2 = xs;  // xs dead after spmm1

    hipMemsetAsync(row_cnt, 0, zero_bytes, stream);  // row_cnt + gs1 + gs2 in one fill

    const int nblk = (N + 255) / 256;
    const int fillBlocks = (E + 255) / 256;
    const int castBlocks = (N * NFEAT / 4 + 255) / 256;

    // CSR build: count -> scan -> finalize -> {fill ∥ cast ∥ W1-transpose}
    k_count<<<fillBlocks, 256, 0, stream>>>(ei, E, row_cnt, rank);
    k_scan1<<<nblk, 256, 0, stream>>>(row_cnt, N, partial, blk);
    k_finalize<<<nblk, 256, 0, stream>>>(partial, blk, row_cnt, N, nblk, row_start, dinv);
    k_fillcast<<<fillBlocks + castBlocks + 128, 256, 0, stream>>>(
        fillBlocks, castBlocks, ei, rank, row_start, E, col_idx, x, dinv, xs,
        N * NFEAT / 4, W1, Wt1);

    const int sg = (N + 3) / 4;
    dim3 gg((N + 127) / 128, 2);

    // t1 = A_hat * x -> aggX (+ fused rvec); then t2 = A_hat * t1 (L2-warm aggX)
    k_spmm<false><<<sg, 256, 0, stream>>>(xs, row_start, row_cnt, col_idx, dinv, aggX, rvec, N);
    k_spmm<true><<<sg, 256, 0, stream>>>(aggX, row_start, row_cnt, col_idx, dinv, t2, nullptr, N);
    // BN1 stats only: h1 = aggX@W1 + b1 (never materialized)
    k_gemm2<NFEAT, true><<<gg, 256, 0, stream>>>(aggX, Wt1, b1, nullptr, nullptr, gs1,
                                                 nullptr, nullptr, N);
    // BN1 fold + WfT = W1*diag(sc1)*W2 + uvec
    k_bnfoldW<<<129, 256, 0, stream>>>(gs1, g1, be1, b1, invN, W1, W2, WfT, uvec);
    // h2pre = t2 @ WfT + rvec*uvec^T + b2, fused BN2 stats
    k_gemm2<NFEAT, true><<<gg, 256, 0, stream>>>(t2, WfT, b2, h2, nullptr, gs2, rvec, uvec, N);
    // BN2 folded into B side: Wtf = diag(sc2)*Wfc (Bt layout), bias2 = of2^T Wfc + bfc
    k_fold2<<<257, 256, 0, stream>>>(gs2, g2, be2, invN, Wfc, bfc, Wtf, bias2);
    // out = h2 @ Wtf + bias2 (plain GEMM, fp32 out)
    k_gemm2<HID, false><<<gg, 256, 0, stream>>>(h2, Wtf, bias2, nullptr, out, nullptr,
                                                nullptr, nullptr, N);
}